// Round 2
// baseline (211.798 us; speedup 1.0000x reference)
//
#include <hip/hip_runtime.h>

// SemanticCaps dynamic routing, fp32. B=128, J=10, K=1152, M=16, I=8.
// Key algebra: b-logits after t iters = u . (v0+...+v_{t-1})  (b starts at 0),
// so no b-logit tensor is materialized — each iteration only needs the
// running sum of v's.
//
// ws layout (floats):
//   u_hat [B][J][K][M]            23,592,960
//   s0p   [B][J][18][M]              368,640   (iter-0 partial sums, c=0.1 fused)
//   v0    [B][J][M]                   20,480
//   vsum  [B][J][M]                   20,480
//   s1    [B][J][M]                   20,480   (atomic accum, memset to 0)
//   s2    [B][J][M]                   20,480   (atomic accum, memset to 0)

#define B_ 128
#define J_ 10
#define K_ 1152
#define M_ 16
#define NT 18            // k-tiles of 64 in uhat
#define CSTR 11          // c_lds row stride (gcd(11,32)=1 -> conflict-free)

// ---------------- Kernel 1: u_hat (coalesced stores) + fused iter-0 partials ---
__global__ __launch_bounds__(256)
void uhat_kernel(const float* __restrict__ x, const float* __restrict__ Ws,
                 float* __restrict__ u_hat, float* __restrict__ s0p) {
    const int b    = blockIdx.x;   // fastest: consecutive blocks share Ws slice in L2
    const int tile = blockIdx.y;   // 18 tiles of 64 k
    const int j    = blockIdx.z;
    const int t    = threadIdx.x;
    const int kl   = t >> 2;       // 0..63
    const int q    = t & 3;        // m-quad 0..3
    const int k    = tile * 64 + kl;

    const float4* xv = (const float4*)(x + ((size_t)b * K_ + k) * 8);
    const float4 x0 = xv[0], x1 = xv[1];

    // Ws[j][k][4q..4q+3][0..7] : 8 float4, contiguous 128 B per thread
    const float4* wv = (const float4*)(Ws + (((size_t)j * K_ + k) * M_ + q * 4) * 8);

    float acc[4];
#pragma unroll
    for (int r = 0; r < 4; ++r) {
        const float4 w0 = wv[2 * r], w1 = wv[2 * r + 1];
        acc[r] = w0.x * x0.x + w0.y * x0.y + w0.z * x0.z + w0.w * x0.w
               + w1.x * x1.x + w1.y * x1.y + w1.z * x1.z + w1.w * x1.w;
    }

    // store: lane-consecutive float4 -> one contiguous 4 KB segment per wave inst
    float4 outv; outv.x = acc[0]; outv.y = acc[1]; outv.z = acc[2]; outv.w = acc[3];
    ((float4*)(u_hat + (((size_t)b * J_ + j) * K_ + k) * M_))[q] = outv;

    // iter-0 partial: sum acc over the 64 k of this tile
    const int wv_id = t >> 6, lane = t & 63;
#pragma unroll
    for (int r = 0; r < 4; ++r) {
        acc[r] += __shfl_xor(acc[r], 4, 64);
        acc[r] += __shfl_xor(acc[r], 8, 64);
        acc[r] += __shfl_xor(acc[r], 16, 64);
        acc[r] += __shfl_xor(acc[r], 32, 64);
    }
    __shared__ float part[4][M_];
    if (lane < 4) {
#pragma unroll
        for (int r = 0; r < 4; ++r) part[wv_id][lane * 4 + r] = acc[r];
    }
    __syncthreads();
    if (t < M_) {
        s0p[(((size_t)b * J_ + j) * NT + tile) * M_ + t] =
            part[0][t] + part[1][t] + part[2][t] + part[3][t];
    }
}

// ---------------- squash kernels (tiny) ----------------------------------------
// MODE 0: v0 = squash(0.1 * sum_tiles s0p)
// MODE 1: v1 = squash(s1); vsum = v0 + v1
// MODE 2: out = squash(s2)
template <int MODE>
__global__ __launch_bounds__(256)
void squash_kernel(const float* __restrict__ sin, const float* __restrict__ v0,
                   float* __restrict__ vout) {
    const int g = blockIdx.x * 256 + threadIdx.x;   // 20480 total
    const int m = g & 15;
    float s;
    if (MODE == 0) {
        const int bj = g >> 4;
        s = 0.f;
#pragma unroll
        for (int tl = 0; tl < NT; ++tl) s += sin[(size_t)bj * (NT * M_) + tl * M_ + m];
        s *= 0.1f;
    } else {
        s = sin[g];
    }
    float sq = s * s;
    sq += __shfl_xor(sq, 1, 64);
    sq += __shfl_xor(sq, 2, 64);
    sq += __shfl_xor(sq, 4, 64);
    sq += __shfl_xor(sq, 8, 64);
    const float n = sqrtf(sq);
    const float v = s * (n / (1.f + sq));
    if (MODE == 1) vout[g] = v0[g] + v;
    else           vout[g] = v;
}

// ---------------- routing iteration: full-width, barrier-light ----------------
// grid (9, 128): seg = k-segment of 128, b = batch. 128 threads (2 waves).
// Phase A: lane owns one k. loop j: load u_j, logit = u_j . vin_j, e=exp,
//          den accumulation — all in regs, no barriers. c -> LDS.
// Phase B: waves sweep j (5 each); lane = (kg,q); contiguous 1KB loads of u
//          (L1/L2-warm from phase A); s partial -> shuffle reduce -> atomicAdd.
__global__ __launch_bounds__(128)
void iter_kernel(const float* __restrict__ u_hat, const float* __restrict__ vin,
                 float* __restrict__ s_out) {
    const int seg = blockIdx.x;      // 0..8
    const int b   = blockIdx.y;
    const int t   = threadIdx.x;

    __shared__ float v_lds[J_ * M_];
    __shared__ float c_lds[128 * CSTR];

    for (int i = t; i < J_ * M_; i += 128) v_lds[i] = vin[(size_t)b * (J_ * M_) + i];
    __syncthreads();

    const int k = seg * 128 + t;
    const float4* ub = (const float4*)u_hat + ((size_t)b * J_ * K_ + k) * 4;

    float e[J_];
    float den = 0.f;
#pragma unroll
    for (int j = 0; j < J_; ++j) {
        const float4* up = ub + (size_t)j * K_ * 4;
        const float4 a0 = up[0], a1 = up[1], a2 = up[2], a3 = up[3];
        const float* vj = v_lds + j * M_;
        float bd = a0.x * vj[0]  + a0.y * vj[1]  + a0.z * vj[2]  + a0.w * vj[3]
                 + a1.x * vj[4]  + a1.y * vj[5]  + a1.z * vj[6]  + a1.w * vj[7]
                 + a2.x * vj[8]  + a2.y * vj[9]  + a2.z * vj[10] + a2.w * vj[11]
                 + a3.x * vj[12] + a3.y * vj[13] + a3.z * vj[14] + a3.w * vj[15];
        e[j] = __expf(bd);
        den += e[j];
    }
    const float inv = 1.f / den;
#pragma unroll
    for (int j = 0; j < J_; ++j) c_lds[t * CSTR + j] = e[j] * inv;
    __syncthreads();

    const int wv = t >> 6, lane = t & 63;
    const int kg = lane >> 2, q = lane & 3;     // lane = kg*4 + q

    for (int jj = wv; jj < J_; jj += 2) {
        float s0 = 0.f, s1 = 0.f, s2 = 0.f, s3 = 0.f;
        const float4* uj = (const float4*)u_hat +
                           (((size_t)b * J_ + jj) * K_ + seg * 128) * 4;
#pragma unroll
        for (int ch = 0; ch < 8; ++ch) {
            const int kk = ch * 16 + kg;
            const float4 u4 = uj[(size_t)kk * 4 + q];   // contiguous 1KB per wave inst
            const float c = c_lds[kk * CSTR + jj];
            s0 += c * u4.x; s1 += c * u4.y; s2 += c * u4.z; s3 += c * u4.w;
        }
#pragma unroll
        for (int off = 4; off <= 32; off <<= 1) {
            s0 += __shfl_xor(s0, off, 64);
            s1 += __shfl_xor(s1, off, 64);
            s2 += __shfl_xor(s2, off, 64);
            s3 += __shfl_xor(s3, off, 64);
        }
        if (lane < 4) {   // lane == q here; holds m = lane*4 + r
            float* dst = s_out + ((size_t)b * J_ + jj) * M_ + lane * 4;
            atomicAdd(dst + 0, s0);
            atomicAdd(dst + 1, s1);
            atomicAdd(dst + 2, s2);
            atomicAdd(dst + 3, s3);
        }
    }
}

extern "C" void kernel_launch(void* const* d_in, const int* in_sizes, int n_in,
                              void* d_out, int out_size, void* d_ws, size_t ws_size,
                              hipStream_t stream) {
    const float* x  = (const float*)d_in[0];
    const float* Ws = (const float*)d_in[1];
    float* out = (float*)d_out;

    float* u_hat = (float*)d_ws;                                  // 23,592,960
    float* s0p   = u_hat + (size_t)B_ * J_ * K_ * M_;             //    368,640
    float* v0    = s0p + (size_t)B_ * J_ * NT * M_;               //     20,480
    float* vsum  = v0 + B_ * J_ * M_;
    float* s1    = vsum + B_ * J_ * M_;
    float* s2    = s1 + B_ * J_ * M_;

    // zero the atomic accumulators (ws is poisoned each launch)
    hipMemsetAsync(s1, 0, 2 * (size_t)B_ * J_ * M_ * sizeof(float), stream);

    dim3 g1(B_, NT, J_);
    uhat_kernel<<<g1, 256, 0, stream>>>(x, Ws, u_hat, s0p);

    squash_kernel<0><<<80, 256, 0, stream>>>(s0p, nullptr, v0);

    dim3 gi(9, B_);
    iter_kernel<<<gi, 128, 0, stream>>>(u_hat, v0, s1);
    squash_kernel<1><<<80, 256, 0, stream>>>(s1, v0, vsum);
    iter_kernel<<<gi, 128, 0, stream>>>(u_hat, vsum, s2);
    squash_kernel<2><<<80, 256, 0, stream>>>(s2, nullptr, out);
}